// Round 4
// baseline (162.838 us; speedup 1.0000x reference)
//
#include <hip/hip_runtime.h>
#include <stdint.h>

typedef __bf16 bf16x8 __attribute__((ext_vector_type(8)));
typedef float f32x16 __attribute__((ext_vector_type(16)));

#define H 128
#define NBINF 11
#define NCHUNK 17          // 8 local + 8 global + 1 binary(11+5 pad)
#define PTOT 640000
#define ROWS 32
#define NT (PTOT / ROWS)   // 20000 tiles
#define GRID 512           // persistent, 2 blocks/CU
#define ASTRIDE 560        // bytes per LDS A row: 280 bf16 (272 + 8 pad)
#define ABUF (ROWS * ASTRIDE) // 17920 B per buffer
#define FSTRIDE 272        // bytes per feat row: 136 bf16
#define PARTOFF 9216       // partial-sum region offset inside buffer

__device__ __align__(16) unsigned short g_wpack[NCHUNK * 4 * 64 * 8]; // [c][nt][lane][8] B-frags
__device__ __align__(16) unsigned short g_wsp[8 * 64 * 8];            // [cs][lane][8] WscT A-frags
__device__ int g_flag; // sparse_idx dword stride: 1 (int32) or 2 (int64)

__device__ __forceinline__ unsigned short f2bf(float f) {
  return (unsigned short)__builtin_bit_cast(unsigned short, (__bf16)f);
}

__global__ void k_flag(const int* __restrict__ sidx) {
  int t = threadIdx.x;
  int v = sidx[2 * t + 1];
  unsigned long long any = __ballot(v != 0);
  if (t == 0) g_flag = (any == 0ull) ? 2 : 1;
}

__global__ void k_pack(const float* __restrict__ Wl, const float* __restrict__ Wg,
                       const float* __restrict__ Wb, const float* __restrict__ Wsc) {
  int tid = blockIdx.x * 256 + threadIdx.x;
  if (tid < NCHUNK * 4 * 64 * 8) {
    int j = tid & 7, l = (tid >> 3) & 63, nt = (tid >> 9) & 3, c = tid >> 11;
    int k = c * 16 + ((l >> 5) << 3) + j;   // K in [0,272)
    int n = nt * 32 + (l & 31);             // N in [0,128)
    float v = 0.f;
    if (k < 128)       v = Wl[k * H + n];
    else if (k < 256)  v = Wg[(k - 128) * H + n];
    else { int kk = k - 256; v = (kk < NBINF) ? Wb[kk * H + n] : 0.f; }
    g_wpack[tid] = f2bf(v);
  }
  if (tid < 8 * 64 * 8) {
    // WscT as MFMA A-frag: row s = l&31, k = cs*16 + (l>>5)*8 + j
    int j = tid & 7, l = (tid >> 3) & 63, cs = tid >> 9;
    int s = l & 31;
    int k = cs * 16 + ((l >> 5) << 3) + j;
    float v = (s < 5) ? Wsc[k * 5 + s] : 0.f;
    g_wsp[tid] = f2bf(v);
  }
}

__device__ __forceinline__ void bar_lgkm() {
  asm volatile("s_waitcnt lgkmcnt(0)" ::: "memory");
  __builtin_amdgcn_s_barrier();
}

__launch_bounds__(256, 2)
__global__ void k_main(const float* __restrict__ lp, const float* __restrict__ gp,
                       const float* __restrict__ bin, const int* __restrict__ sidx,
                       const float* __restrict__ bg, const float* __restrict__ bsc,
                       float* __restrict__ out) {
  __shared__ __align__(16) char sm[2 * ABUF]; // 35840 B
  const int t   = threadIdx.x;
  const int wid = t >> 6;
  const int l   = t & 63;
  const int lr  = l & 31;
  const int lh  = l >> 5;
  const int sflag = g_flag;

  // main-GEMM weight slice (B-frags, 68 VGPR): wave wid owns n-tile wid
  bf16x8 wreg[NCHUNK];
#pragma unroll
  for (int c = 0; c < NCHUNK; ++c)
    wreg[c] = *(const bf16x8*)(g_wpack + ((size_t)(c * 4 + wid) * 64 + l) * 8);
  // score weights: wave wid owns k-chunks {2wid, 2wid+1}
  bf16x8 ws0 = *(const bf16x8*)(g_wsp + ((size_t)(2 * wid + 0) * 64 + l) * 8);
  bf16x8 ws1 = *(const bf16x8*)(g_wsp + ((size_t)(2 * wid + 1) * 64 + l) * 8);

  const float bgv = bg[wid * 32 + lr];

  // two payload sets (depth-2 pipeline), fully static indexing
  float4 payA[8]; float bvA[8];
  float4 payB[8]; float bvB[8];

  auto issue = [&](int tile, float4 (&pay)[8], float (&bv)[8]) {
    const int p0 = tile * ROWS;
#pragma unroll
    for (int i = 0; i < 4; ++i) {
      int v = t + 256 * i;              // 0..1023 : 32B chunk id
      int row = v >> 5, c32 = v & 31;
      const float* src = (c32 < 16)
          ? lp + (size_t)(p0 + row) * H + c32 * 8
          : gp + (size_t)(p0 + row) * H + (c32 - 16) * 8;
      pay[2 * i]     = ((const float4*)src)[0];
      pay[2 * i + 1] = ((const float4*)src)[1];
    }
    if (t < 2 * ROWS) {
      int row = t >> 1, bh = t & 1, prow = p0 + row;
      int bi = sidx[(prow * 3 + 0) * sflag];
      int ii = sidx[(prow * 3 + 1) * sflag];
      int jj = sidx[(prow * 3 + 2) * sflag];
      int base = ((bi * 100 + ii) * 100 + jj) * NBINF;
#pragma unroll
      for (int j = 0; j < 8; ++j) {
        int e = bh * 8 + j;
        bv[j] = (e < NBINF) ? bin[base + e] : 0.f;
      }
    }
  };

  auto commit = [&](char* dst, float4 (&pay)[8], float (&bv)[8]) {
#pragma unroll
    for (int i = 0; i < 4; ++i) {
      int v = t + 256 * i;
      int row = v >> 5, c32 = v & 31;
      float4 a = pay[2 * i], b = pay[2 * i + 1];
      bf16x8 x;
      x[0] = (__bf16)a.x; x[1] = (__bf16)a.y; x[2] = (__bf16)a.z; x[3] = (__bf16)a.w;
      x[4] = (__bf16)b.x; x[5] = (__bf16)b.y; x[6] = (__bf16)b.z; x[7] = (__bf16)b.w;
      *(bf16x8*)(dst + row * ASTRIDE + c32 * 16) = x;
    }
    if (t < 2 * ROWS) {
      int row = t >> 1, bh = t & 1;
      bf16x8 x;
#pragma unroll
      for (int j = 0; j < 8; ++j) x[j] = (__bf16)bv[j];
      *(bf16x8*)(dst + row * ASTRIDE + 512 + bh * 16) = x;
    }
  };

  auto compute = [&](char* buf, int tile) {
    // main GEMM: 17 MFMA, weights in regs. D[p][h]: col=lane=h_local, rows=p
    f32x16 acc = {};
#pragma unroll
    for (int c = 0; c < NCHUNK; ++c) {
      bf16x8 a = *(const bf16x8*)(buf + lr * ASTRIDE + c * 32 + lh * 16);
      acc = __builtin_amdgcn_mfma_f32_32x32x16_bf16(a, wreg[c], acc, 0, 0, 0);
    }
    bar_lgkm(); // BAR1: A reads done; buffer reusable for feats
    // bias + relu -> feat LDS [p][h] bf16 (h = wid*32+lr fixed per lane)
#pragma unroll
    for (int rg = 0; rg < 16; ++rg) {
      int p = (rg & 3) + ((rg >> 2) << 3) + (lh << 2);
      float fv = fmaxf(acc[rg] + bgv, 0.f);
      *(__bf16*)(buf + (size_t)p * FSTRIDE + (size_t)(wid * 32 + lr) * 2) = (__bf16)fv;
    }
    bar_lgkm(); // BAR2: feats visible
    // score partial: wave wid covers k-chunks 2wid,2wid+1. D[s][p], col=lane=p
    f32x16 sacc = {};
    bf16x8 fb0 = *(const bf16x8*)(buf + (size_t)lr * FSTRIDE + (2 * wid) * 32 + lh * 16);
    bf16x8 fb1 = *(const bf16x8*)(buf + (size_t)lr * FSTRIDE + (2 * wid + 1) * 32 + lh * 16);
    sacc = __builtin_amdgcn_mfma_f32_32x32x16_bf16(ws0, fb0, sacc, 0, 0, 0);
    sacc = __builtin_amdgcn_mfma_f32_32x32x16_bf16(ws1, fb1, sacc, 0, 0, 0);
    char* part = buf + PARTOFF; // [s*32+p][w] f32
    if (lh == 0) {
#pragma unroll
      for (int s = 0; s < 4; ++s)  // rg=s -> row s (lh=0)
        *(float*)(part + ((size_t)(s * 32 + lr) * 4 + wid) * 4) = sacc[s];
    } else {
      // rg=0, lh=1 -> row 4
      *(float*)(part + ((size_t)(4 * 32 + lr) * 4 + wid) * 4) = sacc[0];
    }
    bar_lgkm(); // BAR3: partials visible
    if (t < 160) {
      int s = t >> 5, p = t & 31;
      float4 q = *(const float4*)(part + (size_t)t * 16);
      out[(size_t)(tile * ROWS + p) * 5 + s] = q.x + q.y + q.z + q.w + bsc[s];
    }
  };

  // ---- prologue ----
  const int t0 = blockIdx.x;
  issue(t0, payA, bvA);
  commit(sm, payA, bvA);
  issue(t0 + GRID, payB, bvB); // t0+GRID < NT always (512+512 << 20000)
  bar_lgkm();

  // ---- main loop: 2 tiles per iteration ----
  for (int u = t0; u < NT; u += 2 * GRID) {
    const int v = u + GRID;
    // P0: compute tile u from buf0
    if (u + 2 * GRID < NT) issue(u + 2 * GRID, payA, bvA);
    compute(sm, u);
    if (v < NT) commit(sm + ABUF, payB, bvB); // vmcnt lands here (issued 1 phase ago)
    bar_lgkm(); // buf1 ready
    // P1: compute tile v from buf1
    if (v < NT) {
      if (v + 2 * GRID < NT) issue(v + 2 * GRID, payB, bvB);
      compute(sm + ABUF, v);
      if (u + 2 * GRID < NT) commit(sm, payA, bvA);
      bar_lgkm(); // buf0 ready for next iteration
    }
  }
}

extern "C" void kernel_launch(void* const* d_in, const int* in_sizes, int n_in,
                              void* d_out, int out_size, void* d_ws, size_t ws_size,
                              hipStream_t stream) {
  const float* lp  = (const float*)d_in[0];
  const float* gp  = (const float*)d_in[1];
  const float* bin = (const float*)d_in[2];
  const int*   si  = (const int*)d_in[3];
  const float* Wl  = (const float*)d_in[4];
  const float* Wg  = (const float*)d_in[5];
  const float* bg  = (const float*)d_in[6];
  const float* Wb  = (const float*)d_in[7];
  const float* Wsc = (const float*)d_in[8];
  const float* bsc = (const float*)d_in[9];
  float* out = (float*)d_out;

  hipLaunchKernelGGL(k_flag, dim3(1), dim3(64), 0, stream, si);
  hipLaunchKernelGGL(k_pack, dim3(136), dim3(256), 0, stream, Wl, Wg, Wb, Wsc);
  hipLaunchKernelGGL(k_main, dim3(GRID), dim3(256), 0, stream,
                     lp, gp, bin, si, bg, bsc, out);
}

// Round 5
// 144.270 us; speedup vs baseline: 1.1287x; 1.1287x over previous
//
#include <hip/hip_runtime.h>
#include <stdint.h>

typedef __bf16 bf16x8 __attribute__((ext_vector_type(8)));
typedef __bf16 bf16x4 __attribute__((ext_vector_type(4)));
typedef float f32x16 __attribute__((ext_vector_type(16)));

#define H 128
#define NBINF 11
#define NCHUNK 17          // 8 local + 8 global + 1 binary(11+5 pad)
#define PTOT 640000
#define ROWS 32
#define NT (PTOT / ROWS)   // 20000 tiles
#define GRID 768           // persistent, 3 blocks/CU
#define ASTRIDE 560        // bytes per LDS A row: 280 bf16 (272 + 8 pad)
#define ABUF (ROWS * ASTRIDE) // 17920 B per buffer
#define FSTRIDE 272        // bytes per feat row: 136 bf16
#define PARTOFF 9216       // partial-sum region offset inside buffer (feat ends at 8704)

__device__ __align__(16) unsigned short g_wpack[NCHUNK * 4 * 64 * 8]; // [c][nt][lane][8] B-frags
__device__ __align__(16) unsigned short g_wsp[8 * 64 * 8];            // [cs][lane][8] WscT A-frags
__device__ int g_flag; // sparse_idx dword stride: 1 (int32) or 2 (int64)

__device__ __forceinline__ unsigned short f2bf(float f) {
  return (unsigned short)__builtin_bit_cast(unsigned short, (__bf16)f);
}

__global__ void k_flag(const int* __restrict__ sidx) {
  int t = threadIdx.x;
  int v = sidx[2 * t + 1];
  unsigned long long any = __ballot(v != 0);
  if (t == 0) g_flag = (any == 0ull) ? 2 : 1;
}

__global__ void k_pack(const float* __restrict__ Wl, const float* __restrict__ Wg,
                       const float* __restrict__ Wb, const float* __restrict__ Wsc) {
  int tid = blockIdx.x * 256 + threadIdx.x;
  if (tid < NCHUNK * 4 * 64 * 8) {
    int j = tid & 7, l = (tid >> 3) & 63, nt = (tid >> 9) & 3, c = tid >> 11;
    int k = c * 16 + ((l >> 5) << 3) + j;   // K in [0,272)
    int n = nt * 32 + (l & 31);             // N in [0,128)
    float v = 0.f;
    if (k < 128)       v = Wl[k * H + n];
    else if (k < 256)  v = Wg[(k - 128) * H + n];
    else { int kk = k - 256; v = (kk < NBINF) ? Wb[kk * H + n] : 0.f; }
    g_wpack[tid] = f2bf(v);
  }
  if (tid < 8 * 64 * 8) {
    // WscT as MFMA A-frag: row s = l&31, k = cs*16 + (l>>5)*8 + j
    int j = tid & 7, l = (tid >> 3) & 63, cs = tid >> 9;
    int s = l & 31;
    int k = cs * 16 + ((l >> 5) << 3) + j;
    float v = (s < 5) ? Wsc[k * 5 + s] : 0.f;
    g_wsp[tid] = f2bf(v);
  }
}

__device__ __forceinline__ void bar_lgkm() {
  asm volatile("s_waitcnt lgkmcnt(0)" ::: "memory");
  __builtin_amdgcn_s_barrier();
}

__launch_bounds__(256, 3)
__global__ void k_main(const float* __restrict__ lp, const float* __restrict__ gp,
                       const float* __restrict__ bin, const int* __restrict__ sidx,
                       const float* __restrict__ bg, const float* __restrict__ bsc,
                       float* __restrict__ out) {
  __shared__ __align__(16) char sm[2 * ABUF]; // 35840 B -> 3 blocks/CU
  const int t   = threadIdx.x;
  const int wid = t >> 6;
  const int l   = t & 63;
  const int lr  = l & 31;
  const int lh  = l >> 5;
  const int sflag = g_flag;

  // main-GEMM weight slice (B-frags, 68 VGPR): wave wid owns n-tile wid
  bf16x8 wreg[NCHUNK];
#pragma unroll
  for (int c = 0; c < NCHUNK; ++c)
    wreg[c] = *(const bf16x8*)(g_wpack + ((size_t)(c * 4 + wid) * 64 + l) * 8);
  // score weights: wave wid owns k-chunks {2wid, 2wid+1}
  bf16x8 ws0 = *(const bf16x8*)(g_wsp + ((size_t)(2 * wid + 0) * 64 + l) * 8);
  bf16x8 ws1 = *(const bf16x8*)(g_wsp + ((size_t)(2 * wid + 1) * 64 + l) * 8);

  const float bgv = bg[wid * 32 + lr];
  const float bscv = (t < 160) ? bsc[t >> 5] : 0.f;

  // single payload set, depth-1 pipeline (issue -> compute -> commit)
  float4 pay[8];
  float  bv[4];

  auto issue = [&](int tile) {
    const int p0 = tile * ROWS;
#pragma unroll
    for (int i = 0; i < 4; ++i) {
      int v = t + 256 * i;              // 0..1023 : 32B chunk id
      int row = v >> 5, c32 = v & 31;
      const float* src = (c32 < 16)
          ? lp + (size_t)(p0 + row) * H + c32 * 8
          : gp + (size_t)(p0 + row) * H + (c32 - 16) * 8;
      pay[2 * i]     = ((const float4*)src)[0];
      pay[2 * i + 1] = ((const float4*)src)[1];
    }
    if (t < 4 * ROWS) {                 // 128 threads (waves 0,1), 4 per row
      int row = t >> 2, q = t & 3, prow = p0 + row;
      int bi = sidx[(prow * 3 + 0) * sflag];
      int ii = sidx[(prow * 3 + 1) * sflag];
      int jj = sidx[(prow * 3 + 2) * sflag];
      int base = ((bi * 100 + ii) * 100 + jj) * NBINF;
#pragma unroll
      for (int j = 0; j < 4; ++j) {
        int e = 4 * q + j;
        bv[j] = (e < NBINF) ? bin[base + e] : 0.f;
      }
    }
  };

  auto commit = [&](char* dst) {
#pragma unroll
    for (int i = 0; i < 4; ++i) {
      int v = t + 256 * i;
      int row = v >> 5, c32 = v & 31;
      float4 a = pay[2 * i], b = pay[2 * i + 1];
      bf16x8 x;
      x[0] = (__bf16)a.x; x[1] = (__bf16)a.y; x[2] = (__bf16)a.z; x[3] = (__bf16)a.w;
      x[4] = (__bf16)b.x; x[5] = (__bf16)b.y; x[6] = (__bf16)b.z; x[7] = (__bf16)b.w;
      *(bf16x8*)(dst + row * ASTRIDE + c32 * 16) = x;
    }
    if (t < 4 * ROWS) {
      int row = t >> 2, q = t & 3;
      bf16x4 x;
#pragma unroll
      for (int j = 0; j < 4; ++j) x[j] = (__bf16)bv[j];
      *(bf16x4*)(dst + row * ASTRIDE + 512 + q * 8) = x;
    }
  };

  auto compute = [&](char* buf, int tile) {
    // main GEMM: 17 MFMA, weights in regs. D[p][h]: col=lane, rows=p
    f32x16 acc = {};
#pragma unroll
    for (int c = 0; c < NCHUNK; ++c) {
      bf16x8 a = *(const bf16x8*)(buf + lr * ASTRIDE + c * 32 + lh * 16);
      acc = __builtin_amdgcn_mfma_f32_32x32x16_bf16(a, wreg[c], acc, 0, 0, 0);
    }
    bar_lgkm(); // BAR1: A reads done; buffer reusable for feats
    // bias + relu -> feat LDS [p][h] bf16 (h = wid*32+lr fixed per lane)
#pragma unroll
    for (int rg = 0; rg < 16; ++rg) {
      int p = (rg & 3) + ((rg >> 2) << 3) + (lh << 2);
      float fv = fmaxf(acc[rg] + bgv, 0.f);
      *(__bf16*)(buf + (size_t)p * FSTRIDE + (size_t)(wid * 32 + lr) * 2) = (__bf16)fv;
    }
    bar_lgkm(); // BAR2: feats visible
    // score partial: wave wid covers k-chunks 2wid,2wid+1. D[s][p], col=lane=p
    f32x16 sacc = {};
    bf16x8 fb0 = *(const bf16x8*)(buf + (size_t)lr * FSTRIDE + (2 * wid) * 32 + lh * 16);
    bf16x8 fb1 = *(const bf16x8*)(buf + (size_t)lr * FSTRIDE + (2 * wid + 1) * 32 + lh * 16);
    sacc = __builtin_amdgcn_mfma_f32_32x32x16_bf16(ws0, fb0, sacc, 0, 0, 0);
    sacc = __builtin_amdgcn_mfma_f32_32x32x16_bf16(ws1, fb1, sacc, 0, 0, 0);
    // partial layout [w][s*32+p] f32: consecutive-lane writes -> conflict-free
    float* part = (float*)(buf + PARTOFF);
    if (lh == 0) {
#pragma unroll
      for (int s = 0; s < 4; ++s)      // rg=s -> row s (lh=0)
        part[wid * 160 + s * 32 + lr] = sacc[s];
    } else {
      part[wid * 160 + 128 + lr] = sacc[0]; // rg=0, lh=1 -> row 4
    }
    bar_lgkm(); // BAR3: partials visible
    if (t < 160) { // sp = t: s = t>>5, p = t&31; consecutive-lane reads
      float r = part[t] + part[160 + t] + part[320 + t] + part[480 + t];
      out[(size_t)(tile * ROWS + (t & 31)) * 5 + (t >> 5)] = r + bscv;
    }
  };

  // ---- prologue ----
  const int t0 = blockIdx.x;
  issue(t0);
  commit(sm);
  bar_lgkm();

  // ---- main loop (depth-1: issue nxt -> compute cur -> commit nxt) ----
  int cur = 0;
  for (int u = t0; u < NT; u += GRID) {
    const int nxt = u + GRID;
    if (nxt < NT) issue(nxt);
    compute(sm + cur * ABUF, u);
    if (nxt < NT) commit(sm + (cur ^ 1) * ABUF); // vmcnt lands here
    bar_lgkm(); // next tile's A visible; this tile's stores drained
    cur ^= 1;
  }
}

extern "C" void kernel_launch(void* const* d_in, const int* in_sizes, int n_in,
                              void* d_out, int out_size, void* d_ws, size_t ws_size,
                              hipStream_t stream) {
  const float* lp  = (const float*)d_in[0];
  const float* gp  = (const float*)d_in[1];
  const float* bin = (const float*)d_in[2];
  const int*   si  = (const int*)d_in[3];
  const float* Wl  = (const float*)d_in[4];
  const float* Wg  = (const float*)d_in[5];
  const float* bg  = (const float*)d_in[6];
  const float* Wb  = (const float*)d_in[7];
  const float* Wsc = (const float*)d_in[8];
  const float* bsc = (const float*)d_in[9];
  float* out = (float*)d_out;

  hipLaunchKernelGGL(k_flag, dim3(1), dim3(64), 0, stream, si);
  hipLaunchKernelGGL(k_pack, dim3(136), dim3(256), 0, stream, Wl, Wg, Wb, Wsc);
  hipLaunchKernelGGL(k_main, dim3(GRID), dim3(256), 0, stream,
                     lp, gp, bin, si, bg, bsc, out);
}